// Round 13
// baseline (2003.377 us; speedup 1.0000x reference)
//
#include <hip/hip_runtime.h>

#define BATCH 1024
#define TSEQ  512
#define DIN   64
#define H     128
#define NCLS  10
#define BM    16
#define NTHREADS 512
#define NCONS 64
#define TSTRIDE ((size_t)64 * 8192)   /* halfs per t-slice of preact buffer */

typedef _Float16 h16;
typedef __attribute__((ext_vector_type(2))) _Float16 half2v;
typedef __attribute__((ext_vector_type(4))) _Float16 half4v;
typedef __attribute__((ext_vector_type(8))) _Float16 half8v;
typedef __attribute__((ext_vector_type(2))) float f32x2;
typedef __attribute__((ext_vector_type(4))) float f32x4;

// Swizzled staging layout (units: halfs) for a 16-row x K-col fp16 tile.
// chunk(m, kg) = kg*16 + (m ^ (kg&7)); element (m,k) at chunk*8 + (k&7).
__device__ __forceinline__ int stg_addr(int m, int k) {
    const int kg = k >> 3;
    return (((kg << 4) + (m ^ (kg & 7))) << 3) + (k & 7);
}

#define SCALE_G (-2.8853900817779268f)   /* -2*log2(e): tanh gates */
#define SCALE_S (-1.4426950408889634f)   /* -log2(e):   sigmoid gates */

#define MFMA16(A, B, C) __builtin_amdgcn_mfma_f32_16x16x32_f16((A), (B), (C), 0, 0, 0)
#define EXP2(v) __builtin_amdgcn_exp2f(v)
#define RCP(v)  __builtin_amdgcn_rcpf(v)

// Fused c update over a 2-element pair (packed f32x2):
//   c' = [c*(1+e_g)(1+e_i) + (1-e_g)(1+e_f)] / [(1+e_g)(1+e_i)(1+e_f)]
#define CMATH(ACC, PAIR, CST, YCV)                                              \
  {                                                                             \
    f32x2 eg = { EXP2(ACC[0][2*(PAIR)]), EXP2(ACC[0][2*(PAIR)+1]) };            \
    f32x2 ei = { EXP2(ACC[1][2*(PAIR)]), EXP2(ACC[1][2*(PAIR)+1]) };            \
    f32x2 ef = { EXP2(ACC[2][2*(PAIR)]), EXP2(ACC[2][2*(PAIR)+1]) };            \
    f32x2 ag = one2 + eg, ai = one2 + ei, af = one2 + ef;                       \
    f32x2 dp  = ag * ai;                                                        \
    f32x2 t1  = (one2 - eg) * af;                                               \
    f32x2 num = CST * dp + t1;                                                  \
    f32x2 den = dp * af;                                                        \
    f32x2 rd  = { RCP(den[0]), RCP(den[1]) };                                   \
    f32x2 c   = num * rd;                                                       \
    CST = c;                                                                    \
    f32x2 yc = c * sg2;                                                         \
    YCV[0] = fminf(yc[0], 126.f);                                               \
    YCV[1] = fminf(yc[1], 126.f);                                               \
  }

// Fused h = tanh(c)*sigma(o):  h = (1-e_c) / ((1+e_c)(1+e_o))
#define HMATH(ACC, PAIR, YCV)                                                   \
  {                                                                             \
    f32x2 ec = { EXP2(YCV[0]), EXP2(YCV[1]) };                                  \
    f32x2 eo = { EXP2(ACC[3][2*(PAIR)]), EXP2(ACC[3][2*(PAIR)+1]) };            \
    f32x2 dh = (one2 + ec) * (one2 + eo);                                       \
    f32x2 nh = one2 - ec;                                                       \
    f32x2 rh = { RCP(dh[0]), RCP(dh[1]) };                                      \
    f32x2 hv = nh * rh;                                                         \
    hw[hwr[2*(PAIR)]]     = (h16)hv[0];                                         \
    hw[hwr[2*(PAIR) + 1]] = (h16)hv[1];                                         \
  }

// unpack 16 preact halfs (2x uint4) into 4 f32x4 accumulators
#define CVTACC(ACC, A0, A1)                                                     \
  {                                                                             \
    half2v u0 = __builtin_bit_cast(half2v, A0.x);                               \
    half2v u1 = __builtin_bit_cast(half2v, A0.y);                               \
    ACC[0] = (f32x4){(float)u0[0], (float)u0[1], (float)u1[0], (float)u1[1]};   \
    half2v u2 = __builtin_bit_cast(half2v, A0.z);                               \
    half2v u3 = __builtin_bit_cast(half2v, A0.w);                               \
    ACC[1] = (f32x4){(float)u2[0], (float)u2[1], (float)u3[0], (float)u3[1]};   \
    half2v u4 = __builtin_bit_cast(half2v, A1.x);                               \
    half2v u5 = __builtin_bit_cast(half2v, A1.y);                               \
    ACC[2] = (f32x4){(float)u4[0], (float)u4[1], (float)u5[0], (float)u5[1]};   \
    half2v u6 = __builtin_bit_cast(half2v, A1.z);                               \
    half2v u7 = __builtin_bit_cast(half2v, A1.w);                               \
    ACC[3] = (f32x4){(float)u6[0], (float)u6[1], (float)u7[0], (float)u7[1]};   \
  }

// common h-phase: ds_read h(t), 16 h-MFMA, fused packed gate math, h-write
#define HBODY(RD, WR, ACCC)                                                     \
    half8v ah0 = *(const half8v*)&RD[ha0];                                      \
    half8v ah1 = *(const half8v*)&RD[ha1];                                      \
    half8v ah2 = *(const half8v*)&RD[ha2];                                      \
    half8v ah3 = *(const half8v*)&RD[ha3];                                      \
    ACCC[0] = MFMA16(ah0, bh[0][0], ACCC[0]);                                   \
    ACCC[1] = MFMA16(ah0, bh[1][0], ACCC[1]);                                   \
    ACCC[2] = MFMA16(ah0, bh[2][0], ACCC[2]);                                   \
    ACCC[0] = MFMA16(ah1, bh[0][1], ACCC[0]);                                   \
    ACCC[1] = MFMA16(ah1, bh[1][1], ACCC[1]);                                   \
    ACCC[2] = MFMA16(ah1, bh[2][1], ACCC[2]);                                   \
    ACCC[0] = MFMA16(ah2, bh[0][2], ACCC[0]);                                   \
    ACCC[1] = MFMA16(ah2, bh[1][2], ACCC[1]);                                   \
    ACCC[2] = MFMA16(ah2, bh[2][2], ACCC[2]);                                   \
    ACCC[0] = MFMA16(ah3, bh[0][3], ACCC[0]);                                   \
    ACCC[1] = MFMA16(ah3, bh[1][3], ACCC[1]);                                   \
    ACCC[2] = MFMA16(ah3, bh[2][3], ACCC[2]);                                   \
    ACCC[3] = MFMA16(ah0, bh[3][0], ACCC[3]);                                   \
    ACCC[3] = MFMA16(ah1, bh[3][1], ACCC[3]);                                   \
    ACCC[3] = MFMA16(ah2, bh[3][2], ACCC[3]);                                   \
    ACCC[3] = MFMA16(ah3, bh[3][3], ACCC[3]);                                   \
    f32x2 yc0, yc1;                                                             \
    CMATH(ACCC, 0, cst01, yc0)                                                  \
    CMATH(ACCC, 1, cst23, yc1)                                                  \
    h16* hw = WR;                                                               \
    HMATH(ACCC, 0, yc0)                                                         \
    HMATH(ACCC, 1, yc1)

// step with producer-covered priming: ACCN <- preact(t+1) from registers,
// 3-deep prefetch of preact(t+3). No x staging.
#define CSTEP_PRE(tcur, RD, WR, ACCC, ACCN)                                     \
  {                                                                             \
    CVTACC(ACCN, ph0, ph1)                                                      \
    ph0 = pn0; ph1 = pn1;                                                       \
    { const uint4* q = (const uint4*)(prelane + (size_t)((tcur) + 3) * TSTRIDE);\
      pn0 = q[0]; pn1 = q[1]; }                                                 \
    __syncthreads();                                                            \
    HBODY(RD, WR, ACCC)                                                         \
  }

// covered priming + x-staging warmup (runs during the last covered chunk)
#define CSTEP_PRE_STG(tcur, RD, WR, XWR, ACCC, ACCN)                            \
  {                                                                             \
    CVTACC(ACCN, ph0, ph1)                                                      \
    ph0 = pn0; ph1 = pn1;                                                       \
    { const uint4* q = (const uint4*)(prelane + (size_t)((tcur) + 3) * TSTRIDE);\
      pn0 = q[0]; pn1 = q[1]; }                                                 \
    *(half2v*)&XWR[xwr] =                                                       \
        __builtin_bit_cast(half2v, __builtin_amdgcn_cvt_pkrtz(xhold[0], xhold[1])); \
    xhold = xnew;                                                               \
    { const int tpre = ((tcur) + 4 < TSEQ) ? (tcur) + 4 : TSEQ - 1;             \
      xnew = *(const f32x2*)(xrow + (size_t)tpre * DIN); }                      \
    __syncthreads();                                                            \
    HBODY(RD, WR, ACCC)                                                         \
  }

// inline x-GEMM priming (r11 path): for uncovered tail chunks
#define CSTEP_X(tcur, RD, WR, XRD, XWR, ACCC, ACCN)                             \
  {                                                                             \
    half8v xf0 = *(const half8v*)&XRD[xa0];                                     \
    half8v xf1 = *(const half8v*)&XRD[xa1];                                     \
    *(half2v*)&XWR[xwr] =                                                       \
        __builtin_bit_cast(half2v, __builtin_amdgcn_cvt_pkrtz(xhold[0], xhold[1])); \
    xhold = xnew;                                                               \
    { const int tpre = ((tcur) + 4 < TSEQ) ? (tcur) + 4 : TSEQ - 1;             \
      xnew = *(const f32x2*)(xrow + (size_t)tpre * DIN); }                      \
    _Pragma("unroll")                                                           \
    for (int G = 0; G < 4; ++G) {                                               \
        ACCN[G] = MFMA16(xf0, bx[G][0], bias_c[G]);                             \
        ACCN[G] = MFMA16(xf1, bx[G][1], ACCN[G]);                               \
    }                                                                           \
    __syncthreads();                                                            \
    HBODY(RD, WR, ACCC)                                                         \
  }

// ============================================================================
// Fused producer/consumer (grid = 256 = NCONS + 192 producers; all blocks
// resource-guaranteed co-resident: 512 thr, 16 KB LDS, bounds (512,2)).
// Producers: preact_x[G][m][n](t) = SC[G]*(b_G + x(t) W_Gx), stored f16 in
// the consumer lane's exact MFMA D-fragment layout, chunked 16 t per flag.
// Consumers: preact-load priming for covered chunks, r11 inline x-GEMM for
// the tail. ncov==0 degenerates to the proven r11 kernel.
// ============================================================================
__global__ __launch_bounds__(NTHREADS, 2)
void lstm_fused(const float* __restrict__ x,
                const float* __restrict__ Wgx, const float* __restrict__ Wgh,
                const float* __restrict__ Wix, const float* __restrict__ Wih,
                const float* __restrict__ Wfx, const float* __restrict__ Wfh,
                const float* __restrict__ Wox, const float* __restrict__ Woh,
                const float* __restrict__ Wph,
                const float* __restrict__ bg, const float* __restrict__ bi,
                const float* __restrict__ bfg, const float* __restrict__ bo,
                const float* __restrict__ bp,
                float* __restrict__ out,
                h16* __restrict__ pre, unsigned* __restrict__ flags,
                int ncov, int ccov)
{
    __shared__ __align__(16) h16 smem[8192];   // 16 KB

    const int tid  = threadIdx.x;
    const int wave = tid >> 6;
    const int lane = tid & 63;
    const int grp  = lane >> 4;
    const int ln   = lane & 15;
    const float SC[4] = {SCALE_G, SCALE_S, SCALE_S, SCALE_S};

    if (blockIdx.x >= NCONS) {
        // ========================= PRODUCER =========================
        if (ncov <= 0) return;
        const int pb = blockIdx.x - NCONS;   // 0..191
        const int b  = pb & 63;
        const int j  = pb >> 6;              // 0..2: chunk stride-3 offset
        const int n  = (wave << 4) + ln;

        half8v bx[4][2];
        f32x4  bias_c[4];
        {
            const float* WX[4] = {Wgx, Wix, Wfx, Wox};
            const float* BB[4] = {bg, bi, bfg, bo};
            #pragma unroll
            for (int G = 0; G < 4; ++G) {
                #pragma unroll
                for (int s = 0; s < 2; ++s) {
                    half8v v;
                    #pragma unroll
                    for (int q = 0; q < 8; ++q)
                        v[q] = (h16)(WX[G][(32*s + 8*grp + q) * H + n] * SC[G]);
                    bx[G][s] = v;
                }
                const float bb = BB[G][n] * SC[G];
                bias_c[G] = (f32x4){bb, bb, bb, bb};
            }
        }

        const int sub  = tid & 63;
        const int srow = sub >> 2;
        const int sk0  = (sub & 3) << 4;
        const int swr0 = stg_addr(srow, sk0);
        const int swr1 = stg_addr(srow, sk0 + 8);
        const float* xg0 = x + ((size_t)(b * BM + srow) * TSEQ) * DIN + sk0;
        const int pxa0 = stg_addr(ln,      8 * grp);
        const int pxa1 = stg_addr(ln, 32 + 8 * grp);
        h16* outbase = pre + (size_t)b * 8192 + wave * 1024 + lane * 16;

        for (int c = j; c < ncov; c += 3) {
            #pragma unroll
            for (int hf = 0; hf < 2; ++hf) {
                const int t0 = (c << 4) + (hf << 3);
                __syncthreads();   // prior half-chunk's LDS reads complete
                {
                    const float* xs = xg0 + (size_t)(t0 + wave) * DIN;
                    f32x4 v0 = *(const f32x4*)(xs);
                    f32x4 v1 = *(const f32x4*)(xs + 4);
                    f32x4 v2 = *(const f32x4*)(xs + 8);
                    f32x4 v3 = *(const f32x4*)(xs + 12);
                    half8v h0, h1;
                    #pragma unroll
                    for (int q = 0; q < 4; ++q) {
                        h0[q] = (h16)v0[q]; h0[4+q] = (h16)v1[q];
                        h1[q] = (h16)v2[q]; h1[4+q] = (h16)v3[q];
                    }
                    *(half8v*)&smem[wave * 1024 + swr0] = h0;
                    *(half8v*)&smem[wave * 1024 + swr1] = h1;
                }
                __syncthreads();
                #pragma unroll
                for (int tt = 0; tt < 8; ++tt) {
                    half8v ax0 = *(const half8v*)&smem[tt * 1024 + pxa0];
                    half8v ax1 = *(const half8v*)&smem[tt * 1024 + pxa1];
                    unsigned u[8];
                    #pragma unroll
                    for (int G = 0; G < 4; ++G) {
                        f32x4 a = MFMA16(ax0, bx[G][0], bias_c[G]);
                        a = MFMA16(ax1, bx[G][1], a);
                        u[2*G]   = __builtin_bit_cast(unsigned, __builtin_amdgcn_cvt_pkrtz(a[0], a[1]));
                        u[2*G+1] = __builtin_bit_cast(unsigned, __builtin_amdgcn_cvt_pkrtz(a[2], a[3]));
                    }
                    uint4* dst = (uint4*)(outbase + (size_t)(t0 + tt) * TSTRIDE);
                    dst[0] = make_uint4(u[0], u[1], u[2], u[3]);
                    dst[1] = make_uint4(u[4], u[5], u[6], u[7]);
                }
            }
            __threadfence();
            __syncthreads();
            if (tid == 0)
                __hip_atomic_store(&flags[b * 32 + c], 1u,
                                   __ATOMIC_RELEASE, __HIP_MEMORY_SCOPE_AGENT);
        }
        return;
    }

    // ========================= CONSUMER =========================
    const int b  = blockIdx.x;
    const int b0 = b * BM;
    const int n  = (wave << 4) + ln;

    half8v bx[4][2];
    half8v bh[4][4];
    f32x4  bias_c[4];
    {
        const float* WX[4] = {Wgx, Wix, Wfx, Wox};
        const float* WH[4] = {Wgh, Wih, Wfh, Woh};
        const float* BB[4] = {bg, bi, bfg, bo};
        #pragma unroll
        for (int G = 0; G < 4; ++G) {
            #pragma unroll
            for (int s = 0; s < 2; ++s) {
                half8v v;
                #pragma unroll
                for (int q = 0; q < 8; ++q)
                    v[q] = (h16)(WX[G][(32*s + 8*grp + q) * H + n] * SC[G]);
                bx[G][s] = v;
            }
            #pragma unroll
            for (int s = 0; s < 4; ++s) {
                half8v v;
                #pragma unroll
                for (int q = 0; q < 8; ++q)
                    v[q] = (h16)(WH[G][(32*s + 8*grp + q) * H + n] * SC[G]);
                bh[G][s] = v;
            }
            const float bb = BB[G][n] * SC[G];
            bias_c[G] = (f32x4){bb, bb, bb, bb};
        }
    }

    const int ha0 = stg_addr(ln,      8 * grp);
    const int ha1 = stg_addr(ln, 32 + 8 * grp);
    const int ha2 = stg_addr(ln, 64 + 8 * grp);
    const int ha3 = stg_addr(ln, 96 + 8 * grp);
    const int xa0 = ha0;
    const int xa1 = ha1;
    int hwr[4];
    #pragma unroll
    for (int r = 0; r < 4; ++r) hwr[r] = stg_addr((grp << 2) + r, n);

    h16* hbuf0 = smem;            // 2048 halfs each
    h16* hbuf1 = smem + 2048;
    h16* xbuf0 = smem + 4096;     // 1024 halfs each
    h16* xbuf1 = smem + 5120;

    const int xm  = tid >> 5;
    const int xk0 = (tid & 31) << 1;
    const int xwr = stg_addr(xm, xk0);
    const float* xrow = x + (size_t)(b0 + xm) * TSEQ * DIN + xk0;

    const h16* prelane = pre + (size_t)b * 8192 + wave * 1024 + lane * 16;
    unsigned* myflags = flags + b * 32;

    const f32x2 one2 = {1.f, 1.f};
    const f32x2 sg2  = {SCALE_G, SCALE_G};

    // ---- prologue
    *(half4v*)&hbuf0[tid << 2] = (half4v)0;    // h(0) = 0
    f32x4 accA[4], accB[4];
    f32x2 xhold = {0.f, 0.f}, xnew = {0.f, 0.f};
    uint4 ph0 = {0,0,0,0}, ph1 = {0,0,0,0}, pn0 = {0,0,0,0}, pn1 = {0,0,0,0};

    if (ccov > 0) {
        if (tid == 0)
            while (__hip_atomic_load(&myflags[0], __ATOMIC_ACQUIRE,
                                     __HIP_MEMORY_SCOPE_AGENT) == 0)
                __builtin_amdgcn_s_sleep(8);
        __syncthreads();
        __threadfence();
        const uint4* q0 = (const uint4*)(prelane);
        uint4 a0 = q0[0], a1 = q0[1];
        CVTACC(accA, a0, a1)
        const uint4* q1 = (const uint4*)(prelane + TSTRIDE);
        ph0 = q1[0]; ph1 = q1[1];
        const uint4* q2 = (const uint4*)(prelane + 2 * TSTRIDE);
        pn0 = q2[0]; pn1 = q2[1];
    } else {
        {
            f32x2 x0 = *(const f32x2*)xrow;
            *(half2v*)&xbuf0[xwr] =
                __builtin_bit_cast(half2v, __builtin_amdgcn_cvt_pkrtz(x0[0], x0[1]));
        }
        __syncthreads();
        {
            half8v xf0 = *(const half8v*)&xbuf0[xa0];
            half8v xf1 = *(const half8v*)&xbuf0[xa1];
            #pragma unroll
            for (int G = 0; G < 4; ++G) {
                accA[G] = MFMA16(xf0, bx[G][0], bias_c[G]);
                accA[G] = MFMA16(xf1, bx[G][1], accA[G]);
            }
        }
        __syncthreads();
        {
            f32x2 x1 = *(const f32x2*)(xrow + DIN);
            *(half2v*)&xbuf0[xwr] =
                __builtin_bit_cast(half2v, __builtin_amdgcn_cvt_pkrtz(x1[0], x1[1]));
            xhold = *(const f32x2*)(xrow + 2 * DIN);
            xnew  = *(const f32x2*)(xrow + 3 * DIN);
        }
        __syncthreads();
    }

    f32x2 cst01 = {0.f, 0.f};
    f32x2 cst23 = {0.f, 0.f};

    for (int t = 0; t < TSEQ; t += 16) {
        const int c = t >> 4;
        if (c < ccov) {
            // flag for chunk c+1 (prefetch reaches t+3 across the boundary)
            if (tid == 0)
                while (__hip_atomic_load(&myflags[c + 1], __ATOMIC_ACQUIRE,
                                         __HIP_MEMORY_SCOPE_AGENT) == 0)
                    __builtin_amdgcn_s_sleep(8);
            __syncthreads();
            __threadfence();
            if (c + 1 < ccov) {
                #pragma unroll
                for (int k = 0; k < 16; k += 2) {
                    CSTEP_PRE(t + k,     hbuf0, hbuf1, accA, accB)
                    CSTEP_PRE(t + k + 1, hbuf1, hbuf0, accB, accA)
                }
            } else {
                // last covered chunk: warm the x-staging pipeline
                xhold = *(const f32x2*)(xrow + (size_t)(t + 2) * DIN);
                xnew  = *(const f32x2*)(xrow + (size_t)(t + 3) * DIN);
                #pragma unroll
                for (int k = 0; k < 16; k += 2) {
                    CSTEP_PRE_STG(t + k,     hbuf0, hbuf1, xbuf1, accA, accB)
                    CSTEP_PRE_STG(t + k + 1, hbuf1, hbuf0, xbuf0, accB, accA)
                }
            }
        } else {
            #pragma unroll
            for (int k = 0; k < 16; k += 2) {
                CSTEP_X(t + k,     hbuf0, hbuf1, xbuf0, xbuf1, accA, accB)
                CSTEP_X(t + k + 1, hbuf1, hbuf0, xbuf1, xbuf0, accB, accA)
            }
        }
    }

    __syncthreads();
    // final h is in hbuf0 (t=511 odd writes hbuf0)
    if (tid < BM * NCLS) {
        const int m = tid / NCLS;
        const int cls = tid - m * NCLS;
        float s = bp[cls];
        #pragma unroll 8
        for (int k = 0; k < H; ++k) {
            float hvv = (float)hbuf0[stg_addr(m, k)];
            s += hvv * Wph[k * NCLS + cls];
        }
        out[(size_t)(b0 + m) * NCLS + cls] = s;
    }
}

extern "C" void kernel_launch(void* const* d_in, const int* in_sizes, int n_in,
                              void* d_out, int out_size, void* d_ws, size_t ws_size,
                              hipStream_t stream) {
    (void)in_sizes; (void)n_in; (void)out_size;
    const size_t FLAGB = 8192;
    int ncov = 0;
    if (ws_size > FLAGB) {
        size_t chunks = (ws_size - FLAGB) / ((size_t)16 << 20);  // 16 MiB per 16-t chunk
        ncov = (int)(chunks > 32 ? 32 : chunks);
    }
    int ccov = (ncov >= 2) ? (ncov - 1) : 0;
    if (ccov == 0) ncov = 0;
    if (ncov > 0)
        hipMemsetAsync(d_ws, 0, FLAGB, stream);
    lstm_fused<<<dim3(256), dim3(NTHREADS), 0, stream>>>(
        (const float*)d_in[0],
        (const float*)d_in[1], (const float*)d_in[2],
        (const float*)d_in[3], (const float*)d_in[4],
        (const float*)d_in[5], (const float*)d_in[6],
        (const float*)d_in[7], (const float*)d_in[8],
        (const float*)d_in[9],
        (const float*)d_in[10], (const float*)d_in[11],
        (const float*)d_in[12], (const float*)d_in[13],
        (const float*)d_in[14],
        (float*)d_out,
        (h16*)((char*)d_ws + FLAGB), (unsigned*)d_ws,
        ncov, ccov);
}

// Round 14
// 379.846 us; speedup vs baseline: 5.2742x; 5.2742x over previous
//
#include <hip/hip_runtime.h>

#define BATCH 1024
#define TSEQ  512
#define DIN   64
#define H     128
#define NCLS  10
#define BM    16
#define NTHREADS 512

typedef _Float16 h16;
typedef __attribute__((ext_vector_type(2))) _Float16 half2v;
typedef __attribute__((ext_vector_type(4))) _Float16 half4v;
typedef __attribute__((ext_vector_type(8))) _Float16 half8v;
typedef __attribute__((ext_vector_type(2))) float f32x2;
typedef __attribute__((ext_vector_type(4))) float f32x4;

// Swizzled staging layout (units: halfs) for a 16-row x K-col fp16 tile.
// chunk(m, kg) = kg*16 + (m ^ (kg&7)); element (m,k) at chunk*8 + (k&7).
// A-frag read: lane(ln,grp) reads chunk(ln, 4s+grp) as one aligned b128;
// 64 distinct chunks per instr -> conflict-free. Writes spread by XOR.
__device__ __forceinline__ int stg_addr(int m, int k) {
    const int kg = k >> 3;
    return (((kg << 4) + (m ^ (kg & 7))) << 3) + (k & 7);
}

#define SCALE_G (-2.8853900817779268f)   /* -2*log2(e): tanh gates */
#define SCALE_S (-1.4426950408889634f)   /* -log2(e):   sigmoid gates */

#define MFMA16(A, B, C) __builtin_amdgcn_mfma_f32_16x16x32_f16((A), (B), (C), 0, 0, 0)
#define EXP2(v) __builtin_amdgcn_exp2f(v)
#define RCP(v)  __builtin_amdgcn_rcpf(v)

// Fused c update over a 2-element pair (packed f32x2 -> v_pk_* ops):
//   c' = [c*(1+e_g)(1+e_i) + (1-e_g)(1+e_f)] / [(1+e_g)(1+e_i)(1+e_f)]
#define CMATH(ACC, PAIR, CST, YCV)                                              \
  {                                                                             \
    f32x2 eg = { EXP2(ACC[0][2*(PAIR)]), EXP2(ACC[0][2*(PAIR)+1]) };            \
    f32x2 ei = { EXP2(ACC[1][2*(PAIR)]), EXP2(ACC[1][2*(PAIR)+1]) };            \
    f32x2 ef = { EXP2(ACC[2][2*(PAIR)]), EXP2(ACC[2][2*(PAIR)+1]) };            \
    f32x2 ag = one2 + eg, ai = one2 + ei, af = one2 + ef;                       \
    f32x2 dp  = ag * ai;                                                        \
    f32x2 t1  = (one2 - eg) * af;                                               \
    f32x2 num = CST * dp + t1;                                                  \
    f32x2 den = dp * af;                                                        \
    f32x2 rd  = { RCP(den[0]), RCP(den[1]) };                                   \
    f32x2 c   = num * rd;                                                       \
    CST = c;                                                                    \
    f32x2 yc = c * sg2;                                                         \
    YCV[0] = fminf(yc[0], 126.f);                                               \
    YCV[1] = fminf(yc[1], 126.f);                                               \
  }

// Fused h = tanh(c)*sigma(o) for a pair, with immediate LDS write
//   h = (1-e_c) / ((1+e_c)(1+e_o))
#define HMATH(ACC, PAIR, YCV)                                                   \
  {                                                                             \
    f32x2 ec = { EXP2(YCV[0]), EXP2(YCV[1]) };                                  \
    f32x2 eo = { EXP2(ACC[3][2*(PAIR)]), EXP2(ACC[3][2*(PAIR)+1]) };            \
    f32x2 dh = (one2 + ec) * (one2 + eo);                                       \
    f32x2 nh = one2 - ec;                                                       \
    f32x2 rh = { RCP(dh[0]), RCP(dh[1]) };                                      \
    f32x2 hv = nh * rh;                                                         \
    hw[hwr[2*(PAIR)]]     = (h16)hv[0];                                         \
    hw[hwr[2*(PAIR) + 1]] = (h16)hv[1];                                         \
  }

// Persistent LSTM: 64 blocks x 16 batch rows, 8 waves/block (2/SIMD).
// Wave w owns gate columns [16w,16w+16) of all 4 gates -> c/h update is
// register-local. Weights in registers as scale-folded fp16 B-fragments.
// Schedule per step: pre-barrier x-pipeline (stage + x-GEMM(t+1) into the
// spare acc buffer, drains under barrier-wait + ds_read); post-barrier
// k-major g/i/f chains, o-chain, packed c-math (overlaps o drain), packed
// h-math + immediate writes.
__global__ __launch_bounds__(NTHREADS, 2)
void lstm_persist(const float* __restrict__ x,
                  const float* __restrict__ Wgx, const float* __restrict__ Wgh,
                  const float* __restrict__ Wix, const float* __restrict__ Wih,
                  const float* __restrict__ Wfx, const float* __restrict__ Wfh,
                  const float* __restrict__ Wox, const float* __restrict__ Woh,
                  const float* __restrict__ Wph,
                  const float* __restrict__ bg, const float* __restrict__ bi,
                  const float* __restrict__ bfg, const float* __restrict__ bo,
                  const float* __restrict__ bp,
                  float* __restrict__ out)
{
    __shared__ __align__(16) h16 hbuf[2][H * BM];    // 2 x 4KB
    __shared__ __align__(16) h16 xbuf[2][DIN * BM];  // 2 x 2KB

    const int tid  = threadIdx.x;
    const int wave = tid >> 6;
    const int lane = tid & 63;
    const int grp  = lane >> 4;
    const int ln   = lane & 15;
    const int b0   = blockIdx.x * BM;
    const int n    = (wave << 4) + ln;   // gate column 0..127

    // ---- weights -> register B-fragments (fp32 -> fp16, scale folded)
    half8v bx[4][2];
    half8v bh[4][4];
    f32x4  bias_c[4];
    {
        const float* WX[4] = {Wgx, Wix, Wfx, Wox};
        const float* WH[4] = {Wgh, Wih, Wfh, Woh};
        const float* BB[4] = {bg, bi, bfg, bo};
        const float  SC[4] = {SCALE_G, SCALE_S, SCALE_S, SCALE_S};
        #pragma unroll
        for (int G = 0; G < 4; ++G) {
            #pragma unroll
            for (int s = 0; s < 2; ++s) {
                half8v v;
                #pragma unroll
                for (int j = 0; j < 8; ++j)
                    v[j] = (h16)(WX[G][(32*s + 8*grp + j) * H + n] * SC[G]);
                bx[G][s] = v;
            }
            #pragma unroll
            for (int s = 0; s < 4; ++s) {
                half8v v;
                #pragma unroll
                for (int j = 0; j < 8; ++j)
                    v[j] = (h16)(WH[G][(32*s + 8*grp + j) * H + n] * SC[G]);
                bh[G][s] = v;
            }
            const float bb = BB[G][n] * SC[G];
            bias_c[G] = (f32x4){bb, bb, bb, bb};
        }
    }

    // ---- hoisted LDS addresses
    const int ha0 = stg_addr(ln,      8 * grp);
    const int ha1 = stg_addr(ln, 32 + 8 * grp);
    const int ha2 = stg_addr(ln, 64 + 8 * grp);
    const int ha3 = stg_addr(ln, 96 + 8 * grp);
    const int xa0 = ha0;                       // xbuf uses same 16x64 layout
    const int xa1 = ha1;
    int hwr[4];
    #pragma unroll
    for (int r = 0; r < 4; ++r) hwr[r] = stg_addr((grp << 2) + r, n);

    // ---- x stager: ALL 512 threads, 2 floats (8B) each
    const int xm  = tid >> 5;             // row 0..15
    const int xk0 = (tid & 31) << 1;      // k 0,2,...,62
    const int xwr = stg_addr(xm, xk0);    // b32-aligned (xk0 even)
    const float* xrow = x + (size_t)(b0 + xm) * TSEQ * DIN + xk0;

    const f32x2 one2 = {1.f, 1.f};
    const f32x2 sg2  = {SCALE_G, SCALE_G};

    // ---- prologue: zero h(0); prime accA with bias + x(0)-part;
    //      leave xbuf[0]=x(1), xhold=x(2), xnew=x(3).
    *(half4v*)&hbuf[0][tid << 2] = (half4v)0;
    {
        f32x2 x0 = *(const f32x2*)xrow;
        *(half2v*)&xbuf[0][xwr] =
            __builtin_bit_cast(half2v, __builtin_amdgcn_cvt_pkrtz(x0[0], x0[1]));
    }
    __syncthreads();

    f32x4 accA[4], accB[4];
    {
        half8v xf0 = *(const half8v*)&xbuf[0][xa0];
        half8v xf1 = *(const half8v*)&xbuf[0][xa1];
        #pragma unroll
        for (int G = 0; G < 4; ++G) {
            accA[G] = MFMA16(xf0, bx[G][0], bias_c[G]);
            accA[G] = MFMA16(xf1, bx[G][1], accA[G]);
        }
    }
    __syncthreads();   // protect xbuf[0] overwrite below

    f32x2 xhold, xnew;
    {
        f32x2 x1 = *(const f32x2*)(xrow + DIN);      // x(1)
        *(half2v*)&xbuf[0][xwr] =
            __builtin_bit_cast(half2v, __builtin_amdgcn_cvt_pkrtz(x1[0], x1[1]));
        xhold = *(const f32x2*)(xrow + 2 * DIN);     // x(2)
        xnew  = *(const f32x2*)(xrow + 3 * DIN);     // x(3)
    }
    __syncthreads();   // x(1) visible before STEP(0)'s pre-barrier read

    f32x2 cst01 = {0.f, 0.f};
    f32x2 cst23 = {0.f, 0.f};

// One LSTM step. ACCC = bias + x(t)-part (primed by the previous step's
// pre-barrier x-GEMM); ACCN receives bias + x(t+1)-part.
#define STEP(p_, tcur, ACCC, ACCN)                                              \
  {                                                                             \
    /* ===== x-phase (pre-barrier): independent of h(t) ===== */                \
    half8v xf0 = *(const half8v*)&xbuf[p_][xa0];    /* x(tcur+1) */             \
    half8v xf1 = *(const half8v*)&xbuf[p_][xa1];                                \
    *(half2v*)&xbuf[p_ ^ 1][xwr] =                                              \
        __builtin_bit_cast(half2v, __builtin_amdgcn_cvt_pkrtz(xhold[0], xhold[1])); \
    xhold = xnew;                                                               \
    const int tpre = ((tcur) + 4 < TSEQ) ? (tcur) + 4 : TSEQ - 1;               \
    xnew = *(const f32x2*)(xrow + (size_t)tpre * DIN);                          \
    _Pragma("unroll")                                                           \
    for (int G = 0; G < 4; ++G) {                                               \
        ACCN[G] = MFMA16(xf0, bx[G][0], bias_c[G]);                             \
        ACCN[G] = MFMA16(xf1, bx[G][1], ACCN[G]);                               \
    }                                                                           \
    __syncthreads();                                                            \
    /* ===== h-phase ===== */                                                   \
    half8v ah0 = *(const half8v*)&hbuf[p_][ha0];                                \
    half8v ah1 = *(const half8v*)&hbuf[p_][ha1];                                \
    half8v ah2 = *(const half8v*)&hbuf[p_][ha2];                                \
    half8v ah3 = *(const half8v*)&hbuf[p_][ha3];                                \
    /* k-major over g,i,f: same-acc dependency distance = 3 */                  \
    ACCC[0] = MFMA16(ah0, bh[0][0], ACCC[0]);                                   \
    ACCC[1] = MFMA16(ah0, bh[1][0], ACCC[1]);                                   \
    ACCC[2] = MFMA16(ah0, bh[2][0], ACCC[2]);                                   \
    ACCC[0] = MFMA16(ah1, bh[0][1], ACCC[0]);                                   \
    ACCC[1] = MFMA16(ah1, bh[1][1], ACCC[1]);                                   \
    ACCC[2] = MFMA16(ah1, bh[2][1], ACCC[2]);                                   \
    ACCC[0] = MFMA16(ah2, bh[0][2], ACCC[0]);                                   \
    ACCC[1] = MFMA16(ah2, bh[1][2], ACCC[1]);                                   \
    ACCC[2] = MFMA16(ah2, bh[2][2], ACCC[2]);                                   \
    ACCC[0] = MFMA16(ah3, bh[0][3], ACCC[0]);                                   \
    ACCC[1] = MFMA16(ah3, bh[1][3], ACCC[1]);                                   \
    ACCC[2] = MFMA16(ah3, bh[2][3], ACCC[2]);                                   \
    /* o-chain: drains under the packed c-math below */                         \
    ACCC[3] = MFMA16(ah0, bh[3][0], ACCC[3]);                                   \
    ACCC[3] = MFMA16(ah1, bh[3][1], ACCC[3]);                                   \
    ACCC[3] = MFMA16(ah2, bh[3][2], ACCC[3]);                                   \
    ACCC[3] = MFMA16(ah3, bh[3][3], ACCC[3]);                                   \
    f32x2 yc0, yc1;                                                             \
    CMATH(ACCC, 0, cst01, yc0)                                                  \
    CMATH(ACCC, 1, cst23, yc1)                                                  \
    h16* hw = hbuf[p_ ^ 1];                                                     \
    HMATH(ACCC, 0, yc0)                                                         \
    HMATH(ACCC, 1, yc1)                                                         \
  }

    for (int t = 0; t < TSEQ; t += 2) {
        STEP(0, t,     accA, accB)
        STEP(1, t + 1, accB, accA)
    }
#undef STEP

    __syncthreads();
    // final h is in hbuf[0] (t=511 writes p^1 = 0)
    if (tid < BM * NCLS) {
        const int m = tid / NCLS;
        const int cls = tid - m * NCLS;
        float s = bp[cls];
        #pragma unroll 8
        for (int k = 0; k < H; ++k) {
            float hvv = (float)hbuf[0][stg_addr(m, k)];
            s += hvv * Wph[k * NCLS + cls];
        }
        out[(size_t)(b0 + m) * NCLS + cls] = s;
    }
}

extern "C" void kernel_launch(void* const* d_in, const int* in_sizes, int n_in,
                              void* d_out, int out_size, void* d_ws, size_t ws_size,
                              hipStream_t stream) {
    (void)in_sizes; (void)n_in; (void)d_ws; (void)ws_size; (void)out_size;
    lstm_persist<<<dim3(BATCH / BM), dim3(NTHREADS), 0, stream>>>(
        (const float*)d_in[0],
        (const float*)d_in[1], (const float*)d_in[2],
        (const float*)d_in[3], (const float*)d_in[4],
        (const float*)d_in[5], (const float*)d_in[6],
        (const float*)d_in[7], (const float*)d_in[8],
        (const float*)d_in[9],
        (const float*)d_in[10], (const float*)d_in[11],
        (const float*)d_in[12], (const float*)d_in[13],
        (const float*)d_in[14],
        (float*)d_out);
}